// Round 8
// baseline (10051.253 us; speedup 1.0000x reference)
//
#include <hip/hip_runtime.h>
#include <math.h>

#define NN 16384
#define SS 2048
#define TT 16
#define RPB 32            // rows per block -> grid 512, 1 block/CU (128KB LDS)

// np.tanh(f32) mimic: evaluate in f64, round once to f32 (~correctly rounded)
__device__ __forceinline__ float tanh_cr(float a) {
    return (float)tanh((double)a);
}

// Swizzle: within chunk c (2048 floats), rotate by 8c floats (32B * c).
// Bank at fixed i over the 64 compute threads (c,s): (8(i+c)+s)%32 -> 2-way. Free.
__device__ __forceinline__ int swz(int f) {
    int c = f >> 11;
    return (c << 11) | ((f + (c << 3)) & 2047);
}

// inp[s,t] -> inpT[t,s], f32: tanh(where(u >= 0.01f, u, 0))
__global__ void prep_inp(const float* __restrict__ in, float* __restrict__ inpT) {
    int i = blockIdx.x * blockDim.x + threadIdx.x;
    if (i < SS * TT) {
        int s = i / TT, t = i % TT;
        float v = in[i];
        v = (v >= 0.01f) ? v : 0.0f;
        inpT[t * SS + s] = tanh_cr(v);
    }
}

__global__ void map_init(int* __restrict__ map) {
    int i = blockIdx.x * blockDim.x + threadIdx.x;
    if (i < NN) map[i] = -1;
}

__global__ void map_scatter(const int* __restrict__ idx, int* __restrict__ map) {
    int s = blockIdx.x * blockDim.x + threadIdx.x;
    if (s < SS) map[idx[s]] = s;
}

__device__ __forceinline__ float fold8(float a) {
    a += __shfl_xor(a, 4, 64);
    a += __shfl_xor(a, 1, 64);
    a += __shfl_xor(a, 2, 64);
    return a;
}

// t=0 unchanged from R6 (verified): 8 lanes/row, stripe j = k mod 8.
__global__ __launch_bounds__(256) void step0(const float* __restrict__ W,
                                             const int* __restrict__ idx,
                                             const float* __restrict__ inp0,
                                             float* __restrict__ x_out,
                                             float* __restrict__ out) {
    int gid = blockIdx.x * blockDim.x + threadIdx.x;
    int row = gid >> 3;
    int j   = gid & 7;
    if (row >= NN) return;
    const float* __restrict__ wrow = W + (size_t)row * NN;
    float acc = 0.0f;
    #pragma unroll 16
    for (int k = j; k < SS; k += 8)
        acc = fmaf(wrow[idx[k]], inp0[k], acc);
    float y = fold8(acc);
    if (j == 0) {
        float v = (y >= 0.01f) ? y : 0.0f;
        v = tanh_cr(5.0f * v);
        x_out[row] = v;
        out[(size_t)row * TT + 0] = v;
    }
}

// Stage helpers: 256 threads move one 16384-float (64KB) array.
// Global read: float4 #(k*256+tid) -> contiguous 4KB per k across the block.
__device__ __forceinline__ void stage_load(const float* __restrict__ gsrc,
                                           int tid, float4 (&v)[16]) {
    const float4* g4 = reinterpret_cast<const float4*>(gsrc);
    #pragma unroll
    for (int k = 0; k < 16; ++k)
        v[k] = g4[k * 256 + tid];
}
__device__ __forceinline__ void stage_write(float* __restrict__ ldst,
                                            int tid, const float4 (&v)[16]) {
    #pragma unroll
    for (int k = 0; k < 16; ++k) {
        int f = (k * 256 + tid) << 2;           // logical float index
        *reinterpret_cast<float4*>(&ldst[swz(f)]) = v[k];  // rotation keeps f4 intact
    }
}

// t>=1: bit-identical arithmetic to R6 (8 stripes, fold(4,1,2), NBMAX=2048),
// but W streamed row-contiguously through LDS for full coalescing.
__global__ __launch_bounds__(256, 1) void step_t(const float* __restrict__ W,
                                                 const float* __restrict__ x_in,
                                                 const float* __restrict__ inp_t,
                                                 const int* __restrict__ map,
                                                 float* __restrict__ x_out,
                                                 float* __restrict__ out, int t) {
    __shared__ float lds[32768];   // [0,16384): W row   [16384,32768): x
    int tid  = threadIdx.x;
    int row0 = blockIdx.x * RPB;

    // Prologue: stage x and W row0
    {
        float4 v[16];
        stage_load(x_in, tid, v);
        stage_write(&lds[16384], tid, v);
        stage_load(W + (size_t)row0 * NN, tid, v);
        stage_write(&lds[0], tid, v);
    }
    __syncthreads();

    for (int r = 0; r < RPB; ++r) {
        float4 v[16];
        bool pf = (r + 1 < RPB);
        if (pf) stage_load(W + (size_t)(row0 + r + 1) * NN, tid, v);  // issue early

        if (tid < 64) {   // wave 0: the 64 (chunk,stripe) sequential chains
            int c = tid >> 3, s = tid & 7;
            const float* wl = &lds[c << 11];
            const float* xl = &lds[16384 + (c << 11)];
            int o = (s + (c << 3)) & 2047;      // swizzled offset at i=0
            float acc = 0.0f;
            #pragma unroll 8
            for (int i = 0; i < 256; ++i) {     // k = 8i+s: reference chain order
                acc = fmaf(wl[o], xl[o], acc);
                o = (o + 8) & 2047;
            }
            // fold(4,1,2): every lane of octet c holds csum_c (bit-equal)
            float b = acc + __shfl_xor(acc, 4, 64);
            b += __shfl_xor(b, 1, 64);
            b += __shfl_xor(b, 2, 64);
            // chunk sums combined in chunk order (reference y += per NBMAX chunk)
            float y = __shfl(b, 0, 64);
            #pragma unroll
            for (int c2 = 1; c2 < 8; ++c2) y += __shfl(b, c2 * 8, 64);
            if (tid == 0) {
                int row = row0 + r;
                int m = map[row];
                if (m >= 0) y += inp_t[m];
                float vv = (y >= 0.01f) ? y : 0.0f;
                vv = tanh_cr(5.0f * vv);
                x_out[row] = vv;
                out[(size_t)row * TT + t] = vv;
            }
        }
        __syncthreads();                 // all reads of lds[W] done
        if (pf) stage_write(&lds[0], tid, v);   // vmcnt wait folded in by compiler
        __syncthreads();                 // row r+1 visible
    }
}

extern "C" void kernel_launch(void* const* d_in, const int* in_sizes, int n_in,
                              void* d_out, int out_size, void* d_ws, size_t ws_size,
                              hipStream_t stream) {
    const float* W    = (const float*)d_in[0];
    const float* intt = (const float*)d_in[1];
    const int*   idx  = (const int*)d_in[2];
    float* out = (float*)d_out;

    char* ws = (char*)d_ws;
    float* inpT = (float*)ws;                                   // T*S f32 (128 KiB)
    size_t off = (size_t)TT * SS * 4;
    int*   map  = (int*)(ws + off);                             // N ints (64 KiB)
    off += (size_t)NN * 4;
    float* xa   = (float*)(ws + off);                           // N f32
    float* xb   = xa + NN;                                      // N f32

    prep_inp<<<(SS * TT + 255) / 256, 256, 0, stream>>>(intt, inpT);
    map_init<<<NN / 256, 256, 0, stream>>>(map);
    map_scatter<<<SS / 256, 256, 0, stream>>>(idx, map);

    step0<<<NN * 8 / 256, 256, 0, stream>>>(W, idx, inpT, xa, out);

    float* xi_ = xa;
    float* xo_ = xb;
    for (int t = 1; t < TT; ++t) {
        step_t<<<NN / RPB, 256, 0, stream>>>(W, xi_, inpT + (size_t)t * SS,
                                             map, xo_, out, t);
        float* tmp = xi_; xi_ = xo_; xo_ = tmp;
    }
}

// Round 9
// 5673.384 us; speedup vs baseline: 1.7717x; 1.7717x over previous
//
#include <hip/hip_runtime.h>
#include <math.h>

#define NN 16384
#define SS 2048
#define TT 16
#define RPB 64            // rows per block -> grid 256 = 1 block/CU
#define LPW 16            // global_load_lds instrs per wave per row (64KB/(4*64*16B))

// np.tanh(f32) mimic: evaluate in f64, round once to f32 (~correctly rounded)
__device__ __forceinline__ float tanh_cr(float a) {
    return (float)tanh((double)a);
}

// direct global->LDS DMA, 16B per lane, dest = uniform base + lane*16
#define GLOAD_LDS(g, l) __builtin_amdgcn_global_load_lds( \
    (const __attribute__((address_space(1))) void*)(g),   \
    (__attribute__((address_space(3))) void*)(l), 16, 0, 0)

// inp[s,t] -> inpT[t,s], f32: tanh(where(u >= 0.01f, u, 0))
__global__ void prep_inp(const float* __restrict__ in, float* __restrict__ inpT) {
    int i = blockIdx.x * blockDim.x + threadIdx.x;
    if (i < SS * TT) {
        int s = i / TT, t = i % TT;
        float v = in[i];
        v = (v >= 0.01f) ? v : 0.0f;
        inpT[t * SS + s] = tanh_cr(v);
    }
}

__global__ void map_init(int* __restrict__ map) {
    int i = blockIdx.x * blockDim.x + threadIdx.x;
    if (i < NN) map[i] = -1;
}

__global__ void map_scatter(const int* __restrict__ idx, int* __restrict__ map) {
    int s = blockIdx.x * blockDim.x + threadIdx.x;
    if (s < SS) map[idx[s]] = s;
}

__device__ __forceinline__ float fold8(float a) {
    a += __shfl_xor(a, 4, 64);
    a += __shfl_xor(a, 1, 64);
    a += __shfl_xor(a, 2, 64);
    return a;
}

// t=0 unchanged (verified R6): 8 lanes/row, stripe j = k mod 8.
__global__ __launch_bounds__(256) void step0(const float* __restrict__ W,
                                             const int* __restrict__ idx,
                                             const float* __restrict__ inp0,
                                             float* __restrict__ x_out,
                                             float* __restrict__ out) {
    int gid = blockIdx.x * blockDim.x + threadIdx.x;
    int row = gid >> 3;
    int j   = gid & 7;
    if (row >= NN) return;
    const float* __restrict__ wrow = W + (size_t)row * NN;
    float acc = 0.0f;
    #pragma unroll 16
    for (int k = j; k < SS; k += 8)
        acc = fmaf(wrow[idx[k]], inp0[k], acc);
    float y = fold8(acc);
    if (j == 0) {
        float v = (y >= 0.01f) ? y : 0.0f;
        v = tanh_cr(5.0f * v);
        x_out[row] = v;
        out[(size_t)row * TT + 0] = v;
    }
}

// t>=1: bit-identical arithmetic to R6 (8 stripes, fold(4,1,2), NBMAX=2048).
// W rows streamed contiguously via global_load_lds into a double buffer;
// counted vmcnt(16) keeps the next row's DMA in flight across raw s_barriers.
// x lives in wave0 registers (256/lane, static indices) -> compute has no vmem.
__global__ __launch_bounds__(256, 1) void step_t(const float* __restrict__ W,
                                                 const float* __restrict__ x_in,
                                                 const float* __restrict__ inp_t,
                                                 const int* __restrict__ map,
                                                 float* __restrict__ x_out,
                                                 float* __restrict__ out, int t) {
    __shared__ float bufW[2][NN];          // 2 x 64 KiB
    const int tid  = threadIdx.x;
    const int wid  = tid >> 6;
    const int lane = tid & 63;
    const int row0 = blockIdx.x * RPB;
    const int c = lane >> 3, s = lane & 7; // compute mapping (wave 0): chunk, stripe

    // wave0: preload this lane's x slice x[c*2048 + 8i + s], i=0..255
    float xreg[256];
    if (wid == 0) {
        const float* xg = x_in + (c << 11) + s;
        #pragma unroll
        for (int i = 0; i < 256; ++i) xreg[i] = xg[i << 3];
    }
    asm volatile("s_waitcnt vmcnt(0)" ::: "memory");   // retire x loads pre-pipeline

    // prologue: stage rows row0 -> buf0, row0+1 -> buf1 (16 DMA instrs per wave each)
    #pragma unroll
    for (int k = 0; k < LPW; ++k)
        GLOAD_LDS(W + (size_t)row0 * NN + ((wid * LPW + k) << 8) + (lane << 2),
                  &bufW[0][(wid * LPW + k) << 8]);
    #pragma unroll
    for (int k = 0; k < LPW; ++k)
        GLOAD_LDS(W + (size_t)(row0 + 1) * NN + ((wid * LPW + k) << 8) + (lane << 2),
                  &bufW[1][(wid * LPW + k) << 8]);

    for (int r = 0; r < RPB; ++r) {
        // drain row r's DMA (16 oldest per wave); keep row r+1's 16 in flight
        if (r < RPB - 1) asm volatile("s_waitcnt vmcnt(16)" ::: "memory");
        else             asm volatile("s_waitcnt vmcnt(0)"  ::: "memory");
        __builtin_amdgcn_s_barrier();      // buf[r&1] complete for all waves

        if (wid == 0) {
            const float* wl = &bufW[r & 1][c << 11];
            float acc = 0.0f;
            #pragma unroll
            for (int i = 0; i < 256; ++i)           // k = 8i+s: frozen chain order
                acc = fmaf(wl[(i << 3) + s], xreg[i], acc);
            float b = fold8(acc);                   // fold(4,1,2) within octet c
            float y = __shfl(b, 0, 64);             // chunk sums in chunk order
            #pragma unroll
            for (int c2 = 1; c2 < 8; ++c2) y += __shfl(b, c2 << 3, 64);
            if (lane == 0) {
                int row = row0 + r;
                int m = map[row];
                if (m >= 0) y += inp_t[m];
                float vv = (y >= 0.01f) ? y : 0.0f;
                vv = tanh_cr(5.0f * vv);
                x_out[row] = vv;
                out[(size_t)row * TT + t] = vv;
            }
        }
        __builtin_amdgcn_s_barrier();      // wave0 done reading buf[r&1]

        if (r + 2 < RPB) {                 // stage row r+2 into the freed buffer
            #pragma unroll
            for (int k = 0; k < LPW; ++k)
                GLOAD_LDS(W + (size_t)(row0 + r + 2) * NN + ((wid * LPW + k) << 8) + (lane << 2),
                          &bufW[r & 1][(wid * LPW + k) << 8]);
        }
    }
}

extern "C" void kernel_launch(void* const* d_in, const int* in_sizes, int n_in,
                              void* d_out, int out_size, void* d_ws, size_t ws_size,
                              hipStream_t stream) {
    const float* W    = (const float*)d_in[0];
    const float* intt = (const float*)d_in[1];
    const int*   idx  = (const int*)d_in[2];
    float* out = (float*)d_out;

    char* ws = (char*)d_ws;
    float* inpT = (float*)ws;                                   // T*S f32 (128 KiB)
    size_t off = (size_t)TT * SS * 4;
    int*   map  = (int*)(ws + off);                             // N ints (64 KiB)
    off += (size_t)NN * 4;
    float* xa   = (float*)(ws + off);                           // N f32
    float* xb   = xa + NN;                                      // N f32

    prep_inp<<<(SS * TT + 255) / 256, 256, 0, stream>>>(intt, inpT);
    map_init<<<NN / 256, 256, 0, stream>>>(map);
    map_scatter<<<SS / 256, 256, 0, stream>>>(idx, map);

    step0<<<NN * 8 / 256, 256, 0, stream>>>(W, idx, inpT, xa, out);

    float* xi_ = xa;
    float* xo_ = xb;
    for (int t = 1; t < TT; ++t) {
        step_t<<<NN / RPB, 256, 0, stream>>>(W, xi_, inpT + (size_t)t * SS,
                                             map, xo_, out, t);
        float* tmp = xi_; xi_ = xo_; xo_ = tmp;
    }
}